// Round 4
// baseline (759.653 us; speedup 1.0000x reference)
//
#include <hip/hip_runtime.h>

typedef __attribute__((ext_vector_type(8))) short bf8_t;   // 8 bf16 = 4 VGPRs
typedef __attribute__((ext_vector_type(4))) float f4_t;

#define MFMA16(a, b, c) __builtin_amdgcn_mfma_f32_16x16x32_bf16((a), (b), (c), 0, 0, 0)

// Swizzled weight store (bf16 element offsets). Fragment block (nb,k) = 512
// contiguous elems; lane (l15,quad) reads 16B at loff=(l15*4+quad)*8.
#define OFF_FC1 0          // 64x128   block = nt*4+k
#define OFF_FC2 8192       // 64x192   block = nt*6+k
#define OFF_FC3 20480      // 32x64    block = nt*2+k
#define OFF_AB1 22528      // 256x256  block = nb*8+k
#define OFF_AB2 88064      // 256x256
#define W_CHUNKS 19200

// LDS: 32 rows x ST bf16. cols [0:64) = z_hx -> z2 (in-place, wave-private rows)
//      cols [64:320) = T = tanh(x)[0:128) || tanh(m)[128:256); h1 overlays T after B2.
// ST=328 -> row step 164 words = 4 banks -> balanced b128 access.
#define ST 328
#define T0 64

__device__ __forceinline__ unsigned short f2bf(float f) {
    unsigned int u = __builtin_bit_cast(unsigned int, f);
    u += 0x7FFFu + ((u >> 16) & 1u);               // round-to-nearest-even
    return (unsigned short)(u >> 16);
}

__device__ __forceinline__ float fast_tanh(float x) {
    float e = __builtin_amdgcn_exp2f(x * 2.885390081777927f);
    return 1.0f - 2.0f * __builtin_amdgcn_rcpf(e + 1.0f);
}

// fp32 weights -> bf16, fragment-major swizzle (unchanged from round 3).
__global__ void convert_weights_kernel(const float* __restrict__ fc1w, const float* __restrict__ fc2w,
                                       const float* __restrict__ fc3w, const float* __restrict__ ab1w,
                                       const float* __restrict__ ab2w, unsigned short* __restrict__ wc) {
    int c = blockIdx.x * 256 + threadIdx.x;
    if (c >= W_CHUNKS) return;
    const float* p;
#define SWZ(SRC, LC, K32C, KC)                                                  \
    {                                                                           \
        int lc = (LC);                                                          \
        int quad = lc & 3, l15 = (lc >> 2) & 15, t6 = lc >> 6;                  \
        int k = t6 % (K32C), nb = t6 / (K32C);                                  \
        p = (SRC) + (size_t)(nb * 16 + l15) * (KC) + k * 32 + quad * 8;         \
    }
    if (c < 1024)       SWZ(fc1w, c,          4, 128)
    else if (c < 2560)  SWZ(fc2w, c - 1024,   6, 192)
    else if (c < 2816)  SWZ(fc3w, c - 2560,   2, 64)
    else if (c < 11008) SWZ(ab1w, c - 2816,   8, 256)
    else                SWZ(ab2w, c - 11008,  8, 256)
#undef SWZ
    float4 v0 = *(const float4*)p;
    float4 v1 = *(const float4*)(p + 4);
    ushort4 o0, o1;
    o0.x = f2bf(v0.x); o0.y = f2bf(v0.y); o0.z = f2bf(v0.z); o0.w = f2bf(v0.w);
    o1.x = f2bf(v1.x); o1.y = f2bf(v1.y); o1.z = f2bf(v1.z); o1.w = f2bf(v1.w);
    *(ushort4*)(wc + (size_t)c * 8)     = o0;
    *(ushort4*)(wc + (size_t)c * 8 + 4) = o1;
}

__global__ __launch_bounds__(256, 6)
void actor_fused_kernel(const float* __restrict__ x, const float* __restrict__ m,
                        const float* __restrict__ fc1_b, const float* __restrict__ fc2_b,
                        const float* __restrict__ fc3_b,
                        const float* __restrict__ ab_b1, const float* __restrict__ ab_b2,
                        const float* __restrict__ ab_w3, const float* __restrict__ ab_b3,
                        const unsigned short* __restrict__ wc,
                        float* __restrict__ out, int Brows)
{
    __shared__ __align__(16) unsigned short smem[32 * ST];
    __shared__ float pw[4][32];

    const int t    = threadIdx.x;
    const int w    = t >> 6;
    const int lane = t & 63;
    const int l15  = lane & 15;
    const int quad = lane >> 4;
    const int loff = (l15 * 4 + quad) * 8;     // lane offset within 512-elem fragment block
    const int r0   = blockIdx.x * 32;

    // ---------------- stage: T = tanh(x) || tanh(m) (cooperative, coalesced) ----------------
    {
        const float* xp = x + (size_t)r0 * 128;
        const float* mp = m + (size_t)r0 * 128;
        #pragma unroll
        for (int i = 0; i < 4; i++) {
            int idx = t * 4 + i * 1024;        // [0,4096) over 32x128
            int row = idx >> 7, col = idx & 127;
            float4 v = *(const float4*)(xp + idx);
            float4 g = *(const float4*)(mp + idx);
            ushort4 tx, tm;
            tx.x = f2bf(fast_tanh(v.x)); tx.y = f2bf(fast_tanh(v.y));
            tx.z = f2bf(fast_tanh(v.z)); tx.w = f2bf(fast_tanh(v.w));
            tm.x = f2bf(fast_tanh(g.x)); tm.y = f2bf(fast_tanh(g.y));
            tm.z = f2bf(fast_tanh(g.z)); tm.w = f2bf(fast_tanh(g.w));
            *(ushort4*)&smem[row * ST + T0 + col]       = tx;
            *(ushort4*)&smem[row * ST + T0 + 128 + col] = tm;
        }
    }
    __syncthreads();   // B1: T ready

    f4_t acc[16];      // ab1 accumulators for waves 2,3 (acc[j*2+ms])
    float b1v[8];

    if (w < 2) {
        // ============ message branch, waves 0,1 (wave-private 16 rows) ============
        const int mr = w * 16;

        // ---- fc1: A direct from global x (bf16-cast in reg) ----
        f4_t hx[4] = {f4_t{0,0,0,0}, f4_t{0,0,0,0}, f4_t{0,0,0,0}, f4_t{0,0,0,0}};
        #pragma unroll
        for (int k = 0; k < 4; k++) {
            const float* px = x + (size_t)(r0 + mr + l15) * 128 + k * 32 + quad * 8;
            float4 v0 = *(const float4*)px;
            float4 v1 = *(const float4*)(px + 4);
            bf8_t a;
            a[0] = (short)f2bf(v0.x); a[1] = (short)f2bf(v0.y);
            a[2] = (short)f2bf(v0.z); a[3] = (short)f2bf(v0.w);
            a[4] = (short)f2bf(v1.x); a[5] = (short)f2bf(v1.y);
            a[6] = (short)f2bf(v1.z); a[7] = (short)f2bf(v1.w);
            #pragma unroll
            for (int nt = 0; nt < 4; nt++) {
                bf8_t b = *(const bf8_t*)(wc + OFF_FC1 + (nt * 4 + k) * 512 + loff);
                hx[nt] = MFMA16(a, b, hx[nt]);
            }
        }
        {
            float bia[4], ss[4] = {0, 0, 0, 0};
            #pragma unroll
            for (int nt = 0; nt < 4; nt++) bia[nt] = fc1_b[nt * 16 + l15];
            #pragma unroll
            for (int nt = 0; nt < 4; nt++)
                #pragma unroll
                for (int r = 0; r < 4; r++) { hx[nt][r] += bia[nt]; ss[r] += hx[nt][r] * hx[nt][r]; }
            #pragma unroll
            for (int off = 1; off < 16; off <<= 1)
                #pragma unroll
                for (int r = 0; r < 4; r++) ss[r] += __shfl_xor(ss[r], off, 64);
            float inv[4];
            #pragma unroll
            for (int r = 0; r < 4; r++) inv[r] = rsqrtf(fmaxf(ss[r], 1e-24f));
            #pragma unroll
            for (int nt = 0; nt < 4; nt++)
                #pragma unroll
                for (int r = 0; r < 4; r++)
                    smem[(mr + quad * 4 + r) * ST + nt * 16 + l15] = f2bf(fast_tanh(hx[nt][r] * inv[r]));
        }
        // no barrier: z region rows are wave-private, DS ops in-order per wave

        // ---- fc2: K=192 = z_hx[0:64) || tanh(m) ----
        f4_t z2[4] = {f4_t{0,0,0,0}, f4_t{0,0,0,0}, f4_t{0,0,0,0}, f4_t{0,0,0,0}};
        #pragma unroll
        for (int k = 0; k < 6; k++) {
            int acol = (k < 2) ? (k * 32 + quad * 8) : (T0 + 128 + (k - 2) * 32 + quad * 8);
            bf8_t a = *(const bf8_t*)&smem[(mr + l15) * ST + acol];
            #pragma unroll
            for (int nt = 0; nt < 4; nt++) {
                bf8_t b = *(const bf8_t*)(wc + OFF_FC2 + (nt * 6 + k) * 512 + loff);
                z2[nt] = MFMA16(a, b, z2[nt]);
            }
        }
        {
            float bia[4];
            #pragma unroll
            for (int nt = 0; nt < 4; nt++) bia[nt] = fc2_b[nt * 16 + l15];
            #pragma unroll
            for (int nt = 0; nt < 4; nt++)
                #pragma unroll
                for (int r = 0; r < 4; r++)
                    smem[(mr + quad * 4 + r) * ST + nt * 16 + l15] = f2bf(fast_tanh(z2[nt][r] + bia[nt]));
        }
    } else {
        // ============ ab1, waves 2,3 (N-split: 128 cols each, all 32 rows) ============
        const int nb0 = (w - 2) * 8;
        #pragma unroll
        for (int i = 0; i < 16; i++) acc[i] = f4_t{0, 0, 0, 0};
        #pragma unroll
        for (int k = 0; k < 8; k++) {
            bf8_t a0 = *(const bf8_t*)&smem[(l15) * ST + T0 + k * 32 + quad * 8];
            bf8_t a1 = *(const bf8_t*)&smem[(16 + l15) * ST + T0 + k * 32 + quad * 8];
            #pragma unroll
            for (int j = 0; j < 8; j++) {
                bf8_t b = *(const bf8_t*)(wc + OFF_AB1 + ((nb0 + j) * 8 + k) * 512 + loff);
                acc[j * 2 + 0] = MFMA16(a0, b, acc[j * 2 + 0]);
                acc[j * 2 + 1] = MFMA16(a1, b, acc[j * 2 + 1]);
            }
        }
        #pragma unroll
        for (int j = 0; j < 8; j++) b1v[j] = ab_b1[nb0 * 16 + j * 16 + l15];
    }
    __syncthreads();   // B2: all T reads done (msg fc2 a-loads + ab1 a-loads)

    if (w < 2) {
        // ---- fc3: K=64 (z2), N=32; then l2norm + msg out ----
        const int mr = w * 16;
        f4_t mg[2] = {f4_t{0,0,0,0}, f4_t{0,0,0,0}};
        #pragma unroll
        for (int k = 0; k < 2; k++) {
            bf8_t a = *(const bf8_t*)&smem[(mr + l15) * ST + k * 32 + quad * 8];
            #pragma unroll
            for (int nt = 0; nt < 2; nt++) {
                bf8_t b = *(const bf8_t*)(wc + OFF_FC3 + (nt * 2 + k) * 512 + loff);
                mg[nt] = MFMA16(a, b, mg[nt]);
            }
        }
        float bia[2], ss[4] = {0, 0, 0, 0};
        #pragma unroll
        for (int nt = 0; nt < 2; nt++) bia[nt] = fc3_b[nt * 16 + l15];
        #pragma unroll
        for (int nt = 0; nt < 2; nt++)
            #pragma unroll
            for (int r = 0; r < 4; r++) { mg[nt][r] += bia[nt]; ss[r] += mg[nt][r] * mg[nt][r]; }
        #pragma unroll
        for (int off = 1; off < 16; off <<= 1)
            #pragma unroll
            for (int r = 0; r < 4; r++) ss[r] += __shfl_xor(ss[r], off, 64);
        float inv[4];
        #pragma unroll
        for (int r = 0; r < 4; r++) inv[r] = rsqrtf(fmaxf(ss[r], 1e-24f));
        #pragma unroll
        for (int nt = 0; nt < 2; nt++)
            #pragma unroll
            for (int r = 0; r < 4; r++)
                out[(size_t)(r0 + mr + quad * 4 + r) * 32 + nt * 16 + l15] = mg[nt][r] * inv[r];
    } else {
        // ---- h1 = relu(ab1 + b1) -> overlay T cols [T0 : T0+256) ----
        const int nb0 = (w - 2) * 8;
        #pragma unroll
        for (int j = 0; j < 8; j++)
            #pragma unroll
            for (int ms = 0; ms < 2; ms++)
                #pragma unroll
                for (int r = 0; r < 4; r++)
                    smem[(ms * 16 + quad * 4 + r) * ST + T0 + (nb0 + j) * 16 + l15] =
                        f2bf(fmaxf(acc[j * 2 + ms][r] + b1v[j], 0.0f));
    }
    __syncthreads();   // B3: h1 ready

    // ---------------- ab2 + ab3 (all waves, 64-col N chunk each) ----------------
    {
        f4_t a2[8];
        #pragma unroll
        for (int i = 0; i < 8; i++) a2[i] = f4_t{0, 0, 0, 0};
        #pragma unroll
        for (int k = 0; k < 8; k++) {
            bf8_t a0 = *(const bf8_t*)&smem[(l15) * ST + T0 + k * 32 + quad * 8];
            bf8_t a1 = *(const bf8_t*)&smem[(16 + l15) * ST + T0 + k * 32 + quad * 8];
            #pragma unroll
            for (int j = 0; j < 4; j++) {
                bf8_t b = *(const bf8_t*)(wc + OFF_AB2 + ((w * 4 + j) * 8 + k) * 512 + loff);
                a2[j * 2 + 0] = MFMA16(a0, b, a2[j * 2 + 0]);
                a2[j * 2 + 1] = MFMA16(a1, b, a2[j * 2 + 1]);
            }
        }
        float b2v[4], w3v[4];
        #pragma unroll
        for (int j = 0; j < 4; j++) {
            b2v[j] = ab_b2[w * 64 + j * 16 + l15];
            w3v[j] = ab_w3[w * 64 + j * 16 + l15];
        }
        float p[2][4];
        #pragma unroll
        for (int ms = 0; ms < 2; ms++)
            #pragma unroll
            for (int r = 0; r < 4; r++) {
                float s = 0.0f;
                #pragma unroll
                for (int j = 0; j < 4; j++) s += fmaxf(a2[j * 2 + ms][r] + b2v[j], 0.0f) * w3v[j];
                p[ms][r] = s;
            }
        #pragma unroll
        for (int off = 1; off < 16; off <<= 1)
            #pragma unroll
            for (int ms = 0; ms < 2; ms++)
                #pragma unroll
                for (int r = 0; r < 4; r++) p[ms][r] += __shfl_xor(p[ms][r], off, 64);
        if (l15 == 0)
            #pragma unroll
            for (int ms = 0; ms < 2; ms++)
                #pragma unroll
                for (int r = 0; r < 4; r++) pw[w][ms * 16 + quad * 4 + r] = p[ms][r];
    }
    __syncthreads();   // B4: pw ready
    if (t < 32) {
        float a = pw[0][t] + pw[1][t] + pw[2][t] + pw[3][t] + ab_b3[0];
        out[(size_t)Brows * 32 + r0 + t] = fast_tanh(a);   // MAX_ACTION = 1
    }
}

extern "C" void kernel_launch(void* const* d_in, const int* in_sizes, int n_in,
                              void* d_out, int out_size, void* d_ws, size_t ws_size,
                              hipStream_t stream) {
    const float* x     = (const float*)d_in[0];
    const float* m     = (const float*)d_in[1];
    const float* fc1_w = (const float*)d_in[2];
    const float* fc1_b = (const float*)d_in[3];
    const float* fc2_w = (const float*)d_in[4];
    const float* fc2_b = (const float*)d_in[5];
    const float* fc3_w = (const float*)d_in[6];
    const float* fc3_b = (const float*)d_in[7];
    const float* ab_w1 = (const float*)d_in[8];
    const float* ab_b1 = (const float*)d_in[9];
    const float* ab_w2 = (const float*)d_in[10];
    const float* ab_b2 = (const float*)d_in[11];
    const float* ab_w3 = (const float*)d_in[12];
    const float* ab_b3 = (const float*)d_in[13];
    float* out = (float*)d_out;
    unsigned short* wc = (unsigned short*)d_ws;
    int Brows = in_sizes[0] / 128;   // 262144

    convert_weights_kernel<<<(W_CHUNKS + 255) / 256, 256, 0, stream>>>(fc1_w, fc2_w, fc3_w, ab_w1, ab_w2, wc);
    actor_fused_kernel<<<Brows / 32, 256, 0, stream>>>(x, m, fc1_b, fc2_b, fc3_b,
                                                       ab_b1, ab_b2, ab_w3, ab_b3, wc, out, Brows);
}